// Round 5
// baseline (1568.365 us; speedup 1.0000x reference)
//
#include <hip/hip_runtime.h>

namespace {

typedef float floatx4 __attribute__((ext_vector_type(4)));
typedef short bf16x8  __attribute__((ext_vector_type(8)));

constexpr int   kThreads = 384;          // 6 waves; wave == head
constexpr float kScale   = 0.17677669529663687f;  // 32^-0.5

// float -> bf16 (RNE)
__device__ inline short f2bf(float f){
    unsigned u = __builtin_bit_cast(unsigned, f);
    unsigned r = (u + 0x7fffu + ((u >> 16) & 1u)) >> 16;
    return (short)r;
}

__device__ inline floatx4 mfma16(bf16x8 a, bf16x8 b, floatx4 c){
    return __builtin_amdgcn_mfma_f32_16x16x32_bf16(a, b, c, 0, 0, 0);
}

// Weight fragment for lane-group grp, K-step cs: 8 bf16 covering
// cols 32*cs + 4*grp + {0..3} and 32*cs + 16 + 4*grp + {0..3}  (the g-map).
// fp32 weights stay in L2 (~1.2 MB total) -> inline convert, no d_ws needed.
__device__ inline bf16x8 ldwfrag(const float* __restrict__ wrow, int cs, int grp){
    const float* p = wrow + cs * 32 + grp * 4;
    float4 a = *(const float4*)p;
    float4 b = *(const float4*)(p + 16);
    bf16x8 r;
    r[0] = f2bf(a.x); r[1] = f2bf(a.y); r[2] = f2bf(a.z); r[3] = f2bf(a.w);
    r[4] = f2bf(b.x); r[5] = f2bf(b.y); r[6] = f2bf(b.z); r[7] = f2bf(b.w);
    return r;
}

__global__ __launch_bounds__(kThreads, 5)
void swin_mfma(const float* __restrict__ x, const float* __restrict__ qkv_w,
               const float* __restrict__ qkv_b, const float* __restrict__ proj_w,
               const float* __restrict__ proj_b, const float* __restrict__ rpb,
               float* __restrict__ out)
{
    // Shared fragment buffer, used FIRST as X fragments [cs][tt][lane][j],
    // then (after a barrier) reused as O fragments [head][tt][lane][j].
    __shared__ __align__(16) short frag[6][4][64][8];
    __shared__ float rpb_s[1350];   // 225 x 6
    __shared__ float qb_s[576];
    __shared__ float pb_s[192];
    __shared__ int   rgn_s[64];

    const int t      = threadIdx.x;
    const int lane   = t & 63;
    const int wv     = t >> 6;        // wave id == head id
    const int tok_lo = lane & 15;
    const int grp    = lane >> 4;

    // XCD-contiguous swizzle: hardware round-robins blockIdx across 8 XCDs,
    // so give XCD k the contiguous window range [512k, 512k+512). Concurrent
    // blocks on one XCD are then ww/wh-adjacent -> partial 32B-row lines
    // merge in that XCD's L2 (fetch + write amplification fix).
    const int bid = blockIdx.x;
    const int win = (bid & 7) * 512 + (bid >> 3);
    const int b = win >> 10, wh = (win >> 5) & 31, ww = win & 31;

    // ------------- Phase A: stage tables + X fragments -------------------
    for (int i = t; i < 1350; i += kThreads) rpb_s[i] = rpb[i];
    for (int i = t; i < 576;  i += kThreads) qb_s[i]  = qkv_b[i];
    if (t < 192) pb_s[t] = proj_b[t];
    if (t < 64){
        int r = t >> 3, c = t & 7;
        int hs = wh * 8 + r, wsx = ww * 8 + c;
        int rg = (hs < 248) ? 0 : ((hs < 252) ? 1 : 2);
        int cg = (wsx < 248) ? 0 : ((wsx < 252) ? 1 : 2);
        rgn_s[t] = rg * 3 + cg;
    }
    {
        const size_t xbase = (size_t)b * 192 * 65536;
        #pragma unroll
        for (int c0 = 0; c0 < 4; ++c0){
            int comb = c0 * 6 + wv;            // 0..23, all covered by 6 waves
            int cs = comb >> 2, tt = comb & 3;
            int tok = tok_lo + 16 * tt;
            int rr = tok >> 3, cc = tok & 7;
            int h = (wh * 8 + rr + 4) & 255;   // roll(-4)
            int w = (ww * 8 + cc + 4) & 255;
            const float* xp = x + xbase + h * 256 + w;
            bf16x8 f;
            #pragma unroll
            for (int j = 0; j < 8; ++j){
                int ch = 32 * cs + 4 * grp + (j & 3) + 16 * (j >> 2);
                f[j] = f2bf(xp[(size_t)ch << 16]);
            }
            *(bf16x8*)&frag[cs][tt][lane][0] = f;
        }
    }
    __syncthreads();

    const int hd = wv;

    // ------------- QKV GEMMs (transposed Q,K; direct V) ------------------
    floatx4 qa[2][4], ka[2][4], va[4][2];
    {
        floatx4 z = {0.f, 0.f, 0.f, 0.f};
        #pragma unroll
        for (int o = 0; o < 2; ++o)
            #pragma unroll
            for (int tt = 0; tt < 4; ++tt){ qa[o][tt] = z; ka[o][tt] = z; va[tt][o] = z; }
    }
    const int rq0 = 32 * hd + tok_lo;
    #pragma unroll
    for (int cs = 0; cs < 6; ++cs){
        bf16x8 wq[2], wk[2], wvv[2];
        #pragma unroll
        for (int o = 0; o < 2; ++o){
            int r1 = rq0 + 16 * o;
            wq[o]  = ldwfrag(qkv_w + (size_t)r1 * 192,         cs, grp);
            wk[o]  = ldwfrag(qkv_w + (size_t)(192 + r1) * 192, cs, grp);
            wvv[o] = ldwfrag(qkv_w + (size_t)(384 + r1) * 192, cs, grp);
        }
        #pragma unroll
        for (int tt = 0; tt < 4; ++tt){
            bf16x8 xb = *(const bf16x8*)&frag[cs][tt][lane][0];
            qa[0][tt] = mfma16(wq[0], xb, qa[0][tt]);   // D[qch][token]
            qa[1][tt] = mfma16(wq[1], xb, qa[1][tt]);
            ka[0][tt] = mfma16(wk[0], xb, ka[0][tt]);   // D[kch][token]
            ka[1][tt] = mfma16(wk[1], xb, ka[1][tt]);
            va[tt][0] = mfma16(xb, wvv[0], va[tt][0]);  // D[token][vch]
            va[tt][1] = mfma16(xb, wvv[1], va[tt][1]);
        }
    }

    // ------------- bias add + pack Q/K/V operand fragments ---------------
    bf16x8 Qf[4], Kf[4], Vf[2][2];
    {
        float qb[8], kb[8];
        #pragma unroll
        for (int j = 0; j < 8; ++j){
            int d = 16 * (j >> 2) + 4 * grp + (j & 3);
            qb[j] = qb_s[32 * hd + d];
            kb[j] = qb_s[192 + 32 * hd + d];
        }
        #pragma unroll
        for (int tt = 0; tt < 4; ++tt){
            bf16x8 fq, fk;
            #pragma unroll
            for (int j = 0; j < 8; ++j){
                int o = j >> 2, r = j & 3;
                fq[j] = f2bf((qa[o][tt][r] + qb[j]) * kScale);
                fk[j] = f2bf( ka[o][tt][r] + kb[j]);
            }
            Qf[tt] = fq; Kf[tt] = fk;
        }
        #pragma unroll
        for (int it = 0; it < 2; ++it){
            float vb = qb_s[384 + 32 * hd + 16 * it + tok_lo];
            #pragma unroll
            for (int ks = 0; ks < 2; ++ks){
                bf16x8 f;
                #pragma unroll
                for (int j = 0; j < 8; ++j){
                    int r = j & 3, tt = 2 * ks + (j >> 2);
                    f[j] = f2bf(va[tt][it][r] + vb);
                }
                Vf[it][ks] = f;
            }
        }
    }

    // ------------- S = K·Q^T (swapped => D[key][query]) -------------------
    float s[4][4][4];                      // [kt][qt][reg]
    {
        floatx4 z = {0.f, 0.f, 0.f, 0.f};
        #pragma unroll
        for (int kt = 0; kt < 4; ++kt)
            #pragma unroll
            for (int qt = 0; qt < 4; ++qt){
                floatx4 sv = mfma16(Kf[kt], Qf[qt], z);
                #pragma unroll
                for (int r = 0; r < 4; ++r) s[kt][qt][r] = sv[r];
            }
    }
    // bias + shift-mask (analytic rpi; validated)
    {
        const int qrb = tok_lo >> 3, qc = tok_lo & 7;
        const int krb = grp >> 1,    kc0 = 4 * (grp & 1);
        int rq[4];
        #pragma unroll
        for (int qt = 0; qt < 4; ++qt) rq[qt] = rgn_s[16 * qt + tok_lo];
        #pragma unroll
        for (int kt = 0; kt < 4; ++kt){
            int rk[4];
            #pragma unroll
            for (int r = 0; r < 4; ++r) rk[r] = rgn_s[16 * kt + 4 * grp + r];
            #pragma unroll
            for (int qt = 0; qt < 4; ++qt){
                int base = (2 * qt + qrb - 2 * kt - krb + 7) * 15 + (qc - kc0 + 7);
                #pragma unroll
                for (int r = 0; r < 4; ++r){
                    float add = rpb_s[(base - r) * 6 + hd];
                    if (rk[r] != rq[qt]) add -= 100.f;
                    s[kt][qt][r] += add;
                }
            }
        }
    }
    // softmax over keys: 16 local vals + shfl_xor(16), shfl_xor(32)
    float inv[4];
    #pragma unroll
    for (int qt = 0; qt < 4; ++qt){
        float m = -1e30f;
        #pragma unroll
        for (int kt = 0; kt < 4; ++kt)
            #pragma unroll
            for (int r = 0; r < 4; ++r) m = fmaxf(m, s[kt][qt][r]);
        m = fmaxf(m, __shfl_xor(m, 16));
        m = fmaxf(m, __shfl_xor(m, 32));
        float sum = 0.f;
        #pragma unroll
        for (int kt = 0; kt < 4; ++kt)
            #pragma unroll
            for (int r = 0; r < 4; ++r){
                float e = __expf(s[kt][qt][r] - m);
                s[kt][qt][r] = e; sum += e;
            }
        sum += __shfl_xor(sum, 16);
        sum += __shfl_xor(sum, 32);
        inv[qt] = 1.0f / sum;
    }

    // ------------- O^T = V^T·P  (D[d][query]) -----------------------------
    floatx4 oa[2][4];
    {
        floatx4 z = {0.f, 0.f, 0.f, 0.f};
        #pragma unroll
        for (int it = 0; it < 2; ++it)
            #pragma unroll
            for (int qt = 0; qt < 4; ++qt) oa[it][qt] = z;
    }
    #pragma unroll
    for (int ks = 0; ks < 2; ++ks)
        #pragma unroll
        for (int qt = 0; qt < 4; ++qt){
            bf16x8 pf;
            #pragma unroll
            for (int j = 0; j < 8; ++j) pf[j] = f2bf(s[2 * ks + (j >> 2)][qt][j & 3]);
            oa[0][qt] = mfma16(Vf[0][ks], pf, oa[0][qt]);
            oa[1][qt] = mfma16(Vf[1][ks], pf, oa[1][qt]);
        }

    // All waves finished reading X fragments (QKV loop) long ago; sync so we
    // can reuse `frag` as the O-fragment buffer.
    __syncthreads();

    // normalize + stage O fragments for proj
    #pragma unroll
    for (int qt = 0; qt < 4; ++qt){
        bf16x8 f;
        #pragma unroll
        for (int j = 0; j < 8; ++j){
            int it = j >> 2, r = j & 3;
            f[j] = f2bf(oa[it][qt][r] * inv[qt]);
        }
        *(bf16x8*)&frag[wv][qt][lane][0] = f;
    }
    __syncthreads();

    // ------------- proj: D[och][token], each wave owns 32 och -------------
    floatx4 pa[2][4];
    {
        floatx4 z = {0.f, 0.f, 0.f, 0.f};
        #pragma unroll
        for (int o = 0; o < 2; ++o)
            #pragma unroll
            for (int tt = 0; tt < 4; ++tt) pa[o][tt] = z;
    }
    #pragma unroll
    for (int h2 = 0; h2 < 6; ++h2){
        bf16x8 pw[2];
        #pragma unroll
        for (int o = 0; o < 2; ++o){
            int och = 32 * wv + 16 * o + tok_lo;
            pw[o] = ldwfrag(proj_w + (size_t)och * 192, h2, grp);
        }
        #pragma unroll
        for (int tt = 0; tt < 4; ++tt){
            bf16x8 ob = *(const bf16x8*)&frag[h2][tt][lane][0];
            pa[0][tt] = mfma16(pw[0], ob, pa[0][tt]);
            pa[1][tt] = mfma16(pw[1], ob, pa[1][tt]);
        }
    }

    // ------------- epilogue: bias + reverse-shift scatter -----------------
    #pragma unroll
    for (int o = 0; o < 2; ++o)
        #pragma unroll
        for (int tt = 0; tt < 4; ++tt){
            int tok = tok_lo + 16 * tt;
            int rr = tok >> 3, cc = tok & 7;
            int h = (wh * 8 + rr + 4) & 255;
            int w = (ww * 8 + cc + 4) & 255;
            #pragma unroll
            for (int r = 0; r < 4; ++r){
                int och = 32 * wv + 16 * o + 4 * grp + r;
                out[((size_t)(b * 192 + och) << 16) + (h << 8) + w]
                    = pa[o][tt][r] + pb_s[och];
            }
        }
}

} // namespace

extern "C" void kernel_launch(void* const* d_in, const int* in_sizes, int n_in,
                              void* d_out, int out_size, void* d_ws, size_t ws_size,
                              hipStream_t stream) {
    (void)in_sizes; (void)n_in; (void)out_size; (void)d_ws; (void)ws_size;
    const float* x      = (const float*)d_in[0];
    const float* qkv_w  = (const float*)d_in[1];
    const float* qkv_b  = (const float*)d_in[2];
    const float* proj_w = (const float*)d_in[3];
    const float* proj_b = (const float*)d_in[4];
    const float* rpb    = (const float*)d_in[5];
    float* out = (float*)d_out;

    swin_mfma<<<4096, kThreads, 0, stream>>>(x, qkv_w, qkv_b, proj_w, proj_b,
                                             rpb, out);
}